// Round 1
// baseline (1564.493 us; speedup 1.0000x reference)
//
#include <hip/hip_runtime.h>
#include <cstdint>

#define N_NODES 50000
#define N_EDGES 800000
#define IN_FEATS 128
#define HID 64
#define HEADS 3
#define NUM_CLASSES 8
#define ATTN_SLOPE 0.2f
#define ACT_SLOPE 0.01f

__device__ __forceinline__ float lrelu(float x, float s) { return x > 0.f ? x : s * x; }

// ---------- CSR build (once per call; edges are layer-invariant) ----------
__global__ void k_deg(const int* __restrict__ dst, int* __restrict__ deg, int E) {
    int i = blockIdx.x * blockDim.x + threadIdx.x;
    if (i < E) atomicAdd(&deg[dst[i]], 1);
}

// single-block exclusive scan of deg[0..n-1] -> off[0..n], off[n]=E
__global__ void k_scan(const int* __restrict__ deg, int* __restrict__ off, int n) {
    __shared__ int tmp[1024];
    __shared__ int carry_s;
    int tid = threadIdx.x;
    if (tid == 0) carry_s = 0;
    __syncthreads();
    for (int base = 0; base < n; base += 1024) {
        int i = base + tid;
        int v = (i < n) ? deg[i] : 0;
        tmp[tid] = v;
        __syncthreads();
        for (int o = 1; o < 1024; o <<= 1) {
            int t = (tid >= o) ? tmp[tid - o] : 0;
            __syncthreads();
            tmp[tid] += t;
            __syncthreads();
        }
        if (i < n) off[i] = carry_s + tmp[tid] - v;   // exclusive
        int tot = tmp[1023];
        __syncthreads();
        if (tid == 0) carry_s += tot;
        __syncthreads();
    }
    if (tid == 0) off[n] = carry_s;
}

__global__ void k_fill(const int* __restrict__ src, const int* __restrict__ dst,
                       const int* __restrict__ off, int* __restrict__ cur,
                       int* __restrict__ ssrc, int E) {
    int i = blockIdx.x * blockDim.x + threadIdx.x;
    if (i < E) {
        int d = dst[i];
        int p = atomicAdd(&cur[d], 1);
        ssrc[off[d] + p] = src[i];
    }
}

// ---------- feat = h @ W  ([N,din] @ [din,192]) ----------
// 192 threads (thread = output column), 32-row tile, W-chunk + h-tile in LDS.
__global__ __launch_bounds__(192) void k_gemm(const float* __restrict__ h, const float* __restrict__ W,
                                              float* __restrict__ feat, int N, int din) {
    __shared__ float Wl[64 * 192];   // 48 KB
    __shared__ float Hl[32 * 64];    // 8 KB
    int tid = threadIdx.x;
    int row0 = blockIdx.x * 32;
    float acc[32];
#pragma unroll
    for (int r = 0; r < 32; ++r) acc[r] = 0.f;

    for (int k0 = 0; k0 < din; k0 += 64) {
        for (int i = tid; i < 64 * 192; i += 192) Wl[i] = W[k0 * 192 + i];
        for (int i = tid; i < 32 * 64; i += 192) {
            int r = i >> 6, k = i & 63;
            int row = row0 + r;
            Hl[i] = (row < N) ? h[row * din + k0 + k] : 0.f;
        }
        __syncthreads();
        for (int k = 0; k < 64; k += 4) {
            float w0 = Wl[(k + 0) * 192 + tid];
            float w1 = Wl[(k + 1) * 192 + tid];
            float w2 = Wl[(k + 2) * 192 + tid];
            float w3 = Wl[(k + 3) * 192 + tid];
#pragma unroll
            for (int r = 0; r < 32; ++r) {
                float4 h4 = *(const float4*)&Hl[r * 64 + k];   // broadcast, 16B-aligned
                acc[r] += h4.x * w0 + h4.y * w1 + h4.z * w2 + h4.w * w3;
            }
        }
        __syncthreads();
    }
    for (int r = 0; r < 32; ++r) {
        int row = row0 + r;
        if (row < N) feat[row * 192 + tid] = acc[r];
    }
}

// ---------- el/er: per-node attention dots ----------
__global__ __launch_bounds__(256) void k_eler(const float* __restrict__ feat,
                                              const float* __restrict__ al, const float* __restrict__ ar,
                                              float* __restrict__ el, float* __restrict__ er, int N) {
    int wid = (blockIdx.x * blockDim.x + threadIdx.x) >> 6;
    int lane = threadIdx.x & 63;
    if (wid >= N) return;
    for (int h = 0; h < HEADS; ++h) {
        float v = feat[wid * 192 + h * 64 + lane];
        float pl = v * al[h * 64 + lane];
        float pr = v * ar[h * 64 + lane];
        for (int o = 32; o > 0; o >>= 1) {
            pl += __shfl_xor(pl, o);
            pr += __shfl_xor(pr, o);
        }
        if (lane == 0) {
            el[wid * HEADS + h] = pl;
            er[wid * HEADS + h] = pr;
        }
    }
}

// ---------- edge softmax + aggregate + bias + leakyrelu + head-mean ----------
// One wave per destination node; lanes = 64 features. Deterministic per node.
__global__ __launch_bounds__(256) void k_agg(const int* __restrict__ off, const int* __restrict__ ssrc,
                                             const float* __restrict__ el, const float* __restrict__ er,
                                             const float* __restrict__ feat, const float* __restrict__ b,
                                             float* __restrict__ hout, int N) {
    int wid = (blockIdx.x * blockDim.x + threadIdx.x) >> 6;
    int lane = threadIdx.x & 63;
    if (wid >= N) return;
    int start = off[wid], end = off[wid + 1];
    float hsum = 0.f;
    for (int h = 0; h < HEADS; ++h) {
        float er_n = er[wid * HEADS + h];
        // phase A: segment max (lane-strided); cache (s,e) when degree <= 64
        float e0 = -3.4e38f;
        int s0 = 0;
        float mx = -3.4e38f;
        for (int j = start + lane; j < end; j += 64) {
            int s = ssrc[j];
            float e = lrelu(el[s * HEADS + h] + er_n, ATTN_SLOPE);
            s0 = s; e0 = e;
            mx = fmaxf(mx, e);
        }
        for (int o = 32; o > 0; o >>= 1) mx = fmaxf(mx, __shfl_xor(mx, o));
        // phase B: denom + weighted feature gather
        float den = 0.f, acc = 0.f;
        if (end - start <= 64) {
            float ex0 = (start + lane < end) ? __expf(e0 - mx) : 0.f;
            int cnt = end - start;
            for (int t = 0; t < cnt; ++t) {
                float ex = __shfl(ex0, t);
                int s = __shfl(s0, t);
                den += ex;
                acc += ex * feat[s * 192 + h * 64 + lane];
            }
        } else {
            for (int j0 = start; j0 < end; j0 += 64) {
                int jj = j0 + lane;
                int s1 = 0; float ex1 = 0.f;
                if (jj < end) {
                    int s = ssrc[jj];
                    float e = lrelu(el[s * HEADS + h] + er_n, ATTN_SLOPE);
                    s1 = s;
                    ex1 = __expf(e - mx);
                }
                int cnt = min(64, end - j0);
                for (int t = 0; t < cnt; ++t) {
                    float ex = __shfl(ex1, t);
                    int s = __shfl(s1, t);
                    den += ex;
                    acc += ex * feat[s * 192 + h * 64 + lane];
                }
            }
        }
        float val = (end > start) ? (acc / den) : 0.f;
        val += b[h * 64 + lane];
        hsum += lrelu(val, ACT_SLOPE);
    }
    hout[wid * 64 + lane] = hsum * (1.f / 3.f);
}

// ---------- logits = h @ Wo + bo  ([N,64] @ [64,8]) ----------
__global__ __launch_bounds__(256) void k_out(const float* __restrict__ h, const float* __restrict__ Wo,
                                             const float* __restrict__ bo, float* __restrict__ out, int N) {
    __shared__ float Hl[32][65];     // +1 pad: avoid 8-way bank conflict on reads
    __shared__ float Wl[64 * 8];
    int tid = threadIdx.x;
    int n0 = blockIdx.x * 32;
    for (int i = tid; i < 32 * 64; i += 256) {
        int r = i >> 6, k = i & 63;
        Hl[r][k] = (n0 + r < N) ? h[(n0 + r) * 64 + k] : 0.f;
    }
    for (int i = tid; i < 512; i += 256) Wl[i] = Wo[i];
    __syncthreads();
    int r = tid >> 3, c = tid & 7;
    float acc = 0.f;
    for (int k = 0; k < 64; ++k) acc += Hl[r][k] * Wl[k * 8 + c];
    int row = n0 + r;
    if (row < N) out[row * 8 + c] = acc + bo[c];
}

extern "C" void kernel_launch(void* const* d_in, const int* in_sizes, int n_in,
                              void* d_out, int out_size, void* d_ws, size_t ws_size,
                              hipStream_t stream) {
    const float* x  = (const float*)d_in[0];
    const int* src  = (const int*)d_in[1];
    const int* dst  = (const int*)d_in[2];
    const float *W[5], *b[5], *al[5], *ar[5];
    for (int l = 0; l < 5; ++l) {
        W[l]  = (const float*)d_in[3 + l * 4];
        b[l]  = (const float*)d_in[4 + l * 4];
        al[l] = (const float*)d_in[5 + l * 4];
        ar[l] = (const float*)d_in[6 + l * 4];
    }
    const float* Wo = (const float*)d_in[23];
    const float* bo = (const float*)d_in[24];
    float* out = (float*)d_out;

    char* ws = (char*)d_ws;
    auto alloc = [&](size_t bytes) {
        char* p = ws;
        ws += (bytes + 255) & ~size_t(255);
        return p;
    };
    float* feat = (float*)alloc(sizeof(float) * (size_t)N_NODES * 192);
    float* el   = (float*)alloc(sizeof(float) * (size_t)N_NODES * HEADS);
    float* er   = (float*)alloc(sizeof(float) * (size_t)N_NODES * HEADS);
    float* h0   = (float*)alloc(sizeof(float) * (size_t)N_NODES * 64);
    float* h1   = (float*)alloc(sizeof(float) * (size_t)N_NODES * 64);
    int* deg    = (int*)alloc(sizeof(int) * N_NODES);
    int* off    = (int*)alloc(sizeof(int) * (N_NODES + 1));
    int* cur    = (int*)alloc(sizeof(int) * N_NODES);
    int* ssrc   = (int*)alloc(sizeof(int) * N_EDGES);

    // CSR build (graph identical across layers)
    hipMemsetAsync(deg, 0, sizeof(int) * N_NODES, stream);
    hipMemsetAsync(cur, 0, sizeof(int) * N_NODES, stream);
    k_deg<<<(N_EDGES + 255) / 256, 256, 0, stream>>>(dst, deg, N_EDGES);
    k_scan<<<1, 1024, 0, stream>>>(deg, off, N_NODES);
    k_fill<<<(N_EDGES + 255) / 256, 256, 0, stream>>>(src, dst, off, cur, ssrc, N_EDGES);

    const float* hin = x;
    float* hbuf[2] = {h0, h1};
    int din = IN_FEATS;
    for (int l = 0; l < 5; ++l) {
        k_gemm<<<(N_NODES + 31) / 32, 192, 0, stream>>>(hin, W[l], feat, N_NODES, din);
        k_eler<<<(N_NODES * 64 + 255) / 256, 256, 0, stream>>>(feat, al[l], ar[l], el, er, N_NODES);
        float* hn = hbuf[l & 1];
        k_agg<<<(N_NODES * 64 + 255) / 256, 256, 0, stream>>>(off, ssrc, el, er, feat, b[l], hn, N_NODES);
        hin = hn;
        din = HID;
    }
    k_out<<<(N_NODES + 31) / 32, 256, 0, stream>>>(hin, Wo, bo, out, N_NODES);
}

// Round 2
// 1221.061 us; speedup vs baseline: 1.2813x; 1.2813x over previous
//
#include <hip/hip_runtime.h>
#include <cstdint>

#define N_NODES 50000
#define N_EDGES 800000
#define IN_FEATS 128
#define HID 64
#define HEADS 3
#define NUM_CLASSES 8
#define ATTN_SLOPE 0.2f
#define ACT_SLOPE 0.01f

__device__ __forceinline__ float lrelu(float x, float s) { return x > 0.f ? x : s * x; }

// ---------- CSR build (once per call; edges are layer-invariant) ----------
__global__ void k_deg(const int* __restrict__ dst, int* __restrict__ deg, int E) {
    int i = blockIdx.x * blockDim.x + threadIdx.x;
    if (i < E) atomicAdd(&deg[dst[i]], 1);
}

// single-block exclusive scan of deg[0..n-1] -> off[0..n], off[n]=E
__global__ void k_scan(const int* __restrict__ deg, int* __restrict__ off, int n) {
    __shared__ int tmp[1024];
    __shared__ int carry_s;
    int tid = threadIdx.x;
    if (tid == 0) carry_s = 0;
    __syncthreads();
    for (int base = 0; base < n; base += 1024) {
        int i = base + tid;
        int v = (i < n) ? deg[i] : 0;
        tmp[tid] = v;
        __syncthreads();
        for (int o = 1; o < 1024; o <<= 1) {
            int t = (tid >= o) ? tmp[tid - o] : 0;
            __syncthreads();
            tmp[tid] += t;
            __syncthreads();
        }
        if (i < n) off[i] = carry_s + tmp[tid] - v;   // exclusive
        int tot = tmp[1023];
        __syncthreads();
        if (tid == 0) carry_s += tot;
        __syncthreads();
    }
    if (tid == 0) off[n] = carry_s;
}

__global__ void k_fill(const int* __restrict__ src, const int* __restrict__ dst,
                       const int* __restrict__ off, int* __restrict__ cur,
                       int* __restrict__ ssrc, int E) {
    int i = blockIdx.x * blockDim.x + threadIdx.x;
    if (i < E) {
        int d = dst[i];
        int p = atomicAdd(&cur[d], 1);
        ssrc[off[d] + p] = src[i];
    }
}

// ---------- feat = h @ W ([N,din]@[din,192]) + fused el/er epilogue ----------
// 192 threads (thread = output column; wave w == head w), 32-row tile.
__global__ __launch_bounds__(192) void k_gemm(const float* __restrict__ h, const float* __restrict__ W,
                                              const float* __restrict__ al, const float* __restrict__ ar,
                                              float* __restrict__ feat,
                                              float* __restrict__ el, float* __restrict__ er,
                                              int N, int din) {
    __shared__ float Wl[64 * 192];   // 48 KB
    __shared__ float Hl[32 * 64];    // 8 KB
    int tid = threadIdx.x;
    int lane = tid & 63;
    int head = tid >> 6;             // wave index == head index
    int row0 = blockIdx.x * 32;
    float acc[32];
#pragma unroll
    for (int r = 0; r < 32; ++r) acc[r] = 0.f;

    for (int k0 = 0; k0 < din; k0 += 64) {
        for (int i = tid; i < 64 * 192; i += 192) Wl[i] = W[k0 * 192 + i];
        for (int i = tid; i < 32 * 64; i += 192) {
            int r = i >> 6, k = i & 63;
            int row = row0 + r;
            Hl[i] = (row < N) ? h[row * din + k0 + k] : 0.f;
        }
        __syncthreads();
        for (int k = 0; k < 64; k += 4) {
            float w0 = Wl[(k + 0) * 192 + tid];
            float w1 = Wl[(k + 1) * 192 + tid];
            float w2 = Wl[(k + 2) * 192 + tid];
            float w3 = Wl[(k + 3) * 192 + tid];
#pragma unroll
            for (int r = 0; r < 32; ++r) {
                float4 h4 = *(const float4*)&Hl[r * 64 + k];   // broadcast, 16B-aligned
                acc[r] += h4.x * w0 + h4.y * w1 + h4.z * w2 + h4.w * w3;
            }
        }
        __syncthreads();
    }
    float alv = al[tid];   // al[head*64 + lane] == al[tid]
    float arv = ar[tid];
#pragma unroll 4
    for (int r = 0; r < 32; ++r) {
        int row = row0 + r;
        if (row < N) feat[row * 192 + tid] = acc[r];
        float pl = acc[r] * alv;
        float pr = acc[r] * arv;
        for (int o = 32; o > 0; o >>= 1) {
            pl += __shfl_xor(pl, o);
            pr += __shfl_xor(pr, o);
        }
        if (lane == 0 && row < N) {
            el[row * HEADS + head] = pl;
            er[row * HEADS + head] = pr;
        }
    }
}

// ---------- edge softmax + aggregate + bias + leakyrelu + head-mean ----------
// One wave per destination node; lanes = 64 features; all 3 heads in ONE edge
// pass. Per-edge {src, ex0, ex1, ex2} packed to LDS once; inner loop is one
// ds_read_b128 broadcast + 3 independent 256B gathers -> 3 loads in flight.
__global__ __launch_bounds__(256) void k_agg(const int* __restrict__ off, const int* __restrict__ ssrc,
                                             const float* __restrict__ el, const float* __restrict__ er,
                                             const float* __restrict__ feat, const float* __restrict__ b,
                                             float* __restrict__ hout, int N) {
    __shared__ float4 ebuf[4][64];
    int wib = threadIdx.x >> 6;
    int wid = (blockIdx.x * blockDim.x + threadIdx.x) >> 6;
    int lane = threadIdx.x & 63;
    if (wid >= N) return;
    int start = off[wid], end = off[wid + 1];
    int cnt = end - start;
    float er0 = er[wid * HEADS + 0];
    float er1 = er[wid * HEADS + 1];
    float er2 = er[wid * HEADS + 2];
    float acc0 = 0.f, acc1 = 0.f, acc2 = 0.f;
    float den0 = 0.f, den1 = 0.f, den2 = 0.f;

    if (cnt <= 64) {
        int s0 = 0;
        float ea = -3.4e38f, eb = -3.4e38f, ec = -3.4e38f;
        if (lane < cnt) {
            s0 = ssrc[start + lane];
            ea = lrelu(el[s0 * HEADS + 0] + er0, ATTN_SLOPE);
            eb = lrelu(el[s0 * HEADS + 1] + er1, ATTN_SLOPE);
            ec = lrelu(el[s0 * HEADS + 2] + er2, ATTN_SLOPE);
        }
        float ma = ea, mb = eb, mc = ec;
        for (int o = 32; o > 0; o >>= 1) {
            ma = fmaxf(ma, __shfl_xor(ma, o));
            mb = fmaxf(mb, __shfl_xor(mb, o));
            mc = fmaxf(mc, __shfl_xor(mc, o));
        }
        float xa = (lane < cnt) ? __expf(ea - ma) : 0.f;
        float xb = (lane < cnt) ? __expf(eb - mb) : 0.f;
        float xc = (lane < cnt) ? __expf(ec - mc) : 0.f;
        float da = xa, db = xb, dc = xc;
        for (int o = 32; o > 0; o >>= 1) {
            da += __shfl_xor(da, o);
            db += __shfl_xor(db, o);
            dc += __shfl_xor(dc, o);
        }
        den0 = da; den1 = db; den2 = dc;
        ebuf[wib][lane] = make_float4(__int_as_float(s0), xa, xb, xc);
        for (int t = 0; t < cnt; ++t) {
            float4 v = ebuf[wib][t];                 // uniform addr -> broadcast
            const float* fr = feat + (size_t)__float_as_int(v.x) * 192;
            acc0 += v.y * fr[lane];
            acc1 += v.z * fr[64 + lane];
            acc2 += v.w * fr[128 + lane];
        }
    } else {
        // generic fallback (degree > 64): max pre-pass, then chunked passes
        float ma = -3.4e38f, mb = -3.4e38f, mc = -3.4e38f;
        for (int j = start + lane; j < end; j += 64) {
            int s = ssrc[j];
            ma = fmaxf(ma, lrelu(el[s * HEADS + 0] + er0, ATTN_SLOPE));
            mb = fmaxf(mb, lrelu(el[s * HEADS + 1] + er1, ATTN_SLOPE));
            mc = fmaxf(mc, lrelu(el[s * HEADS + 2] + er2, ATTN_SLOPE));
        }
        for (int o = 32; o > 0; o >>= 1) {
            ma = fmaxf(ma, __shfl_xor(ma, o));
            mb = fmaxf(mb, __shfl_xor(mb, o));
            mc = fmaxf(mc, __shfl_xor(mc, o));
        }
        float da = 0.f, db = 0.f, dc = 0.f;
        for (int j0 = start; j0 < end; j0 += 64) {
            int jj = j0 + lane;
            int s0 = 0;
            float xa = 0.f, xb = 0.f, xc = 0.f;
            if (jj < end) {
                s0 = ssrc[jj];
                xa = __expf(lrelu(el[s0 * HEADS + 0] + er0, ATTN_SLOPE) - ma);
                xb = __expf(lrelu(el[s0 * HEADS + 1] + er1, ATTN_SLOPE) - mb);
                xc = __expf(lrelu(el[s0 * HEADS + 2] + er2, ATTN_SLOPE) - mc);
            }
            da += xa; db += xb; dc += xc;
            ebuf[wib][lane] = make_float4(__int_as_float(s0), xa, xb, xc);
            int c = min(64, end - j0);
            for (int t = 0; t < c; ++t) {
                float4 v = ebuf[wib][t];
                const float* fr = feat + (size_t)__float_as_int(v.x) * 192;
                acc0 += v.y * fr[lane];
                acc1 += v.z * fr[64 + lane];
                acc2 += v.w * fr[128 + lane];
            }
        }
        for (int o = 32; o > 0; o >>= 1) {
            da += __shfl_xor(da, o);
            db += __shfl_xor(db, o);
            dc += __shfl_xor(dc, o);
        }
        den0 = da; den1 = db; den2 = dc;
    }

    float v0 = (cnt > 0) ? acc0 / den0 : 0.f;
    float v1 = (cnt > 0) ? acc1 / den1 : 0.f;
    float v2 = (cnt > 0) ? acc2 / den2 : 0.f;
    float hsum = lrelu(v0 + b[lane], ACT_SLOPE)
               + lrelu(v1 + b[64 + lane], ACT_SLOPE)
               + lrelu(v2 + b[128 + lane], ACT_SLOPE);
    hout[wid * 64 + lane] = hsum * (1.f / 3.f);
}

// ---------- logits = h @ Wo + bo  ([N,64] @ [64,8]) ----------
__global__ __launch_bounds__(256) void k_out(const float* __restrict__ h, const float* __restrict__ Wo,
                                             const float* __restrict__ bo, float* __restrict__ out, int N) {
    __shared__ float Hl[32][65];
    __shared__ float Wl[64 * 8];
    int tid = threadIdx.x;
    int n0 = blockIdx.x * 32;
    for (int i = tid; i < 32 * 64; i += 256) {
        int r = i >> 6, k = i & 63;
        Hl[r][k] = (n0 + r < N) ? h[(n0 + r) * 64 + k] : 0.f;
    }
    for (int i = tid; i < 512; i += 256) Wl[i] = Wo[i];
    __syncthreads();
    int r = tid >> 3, c = tid & 7;
    float acc = 0.f;
    for (int k = 0; k < 64; ++k) acc += Hl[r][k] * Wl[k * 8 + c];
    int row = n0 + r;
    if (row < N) out[row * 8 + c] = acc + bo[c];
}

extern "C" void kernel_launch(void* const* d_in, const int* in_sizes, int n_in,
                              void* d_out, int out_size, void* d_ws, size_t ws_size,
                              hipStream_t stream) {
    const float* x  = (const float*)d_in[0];
    const int* src  = (const int*)d_in[1];
    const int* dst  = (const int*)d_in[2];
    const float *W[5], *b[5], *al[5], *ar[5];
    for (int l = 0; l < 5; ++l) {
        W[l]  = (const float*)d_in[3 + l * 4];
        b[l]  = (const float*)d_in[4 + l * 4];
        al[l] = (const float*)d_in[5 + l * 4];
        ar[l] = (const float*)d_in[6 + l * 4];
    }
    const float* Wo = (const float*)d_in[23];
    const float* bo = (const float*)d_in[24];
    float* out = (float*)d_out;

    char* ws = (char*)d_ws;
    auto alloc = [&](size_t bytes) {
        char* p = ws;
        ws += (bytes + 255) & ~size_t(255);
        return p;
    };
    float* feat = (float*)alloc(sizeof(float) * (size_t)N_NODES * 192);
    float* el   = (float*)alloc(sizeof(float) * (size_t)N_NODES * HEADS);
    float* er   = (float*)alloc(sizeof(float) * (size_t)N_NODES * HEADS);
    float* h0   = (float*)alloc(sizeof(float) * (size_t)N_NODES * 64);
    float* h1   = (float*)alloc(sizeof(float) * (size_t)N_NODES * 64);
    int* deg    = (int*)alloc(sizeof(int) * N_NODES);
    int* off    = (int*)alloc(sizeof(int) * (N_NODES + 1));
    int* cur    = (int*)alloc(sizeof(int) * N_NODES);
    int* ssrc   = (int*)alloc(sizeof(int) * N_EDGES);

    hipMemsetAsync(deg, 0, sizeof(int) * N_NODES, stream);
    hipMemsetAsync(cur, 0, sizeof(int) * N_NODES, stream);
    k_deg<<<(N_EDGES + 255) / 256, 256, 0, stream>>>(dst, deg, N_EDGES);
    k_scan<<<1, 1024, 0, stream>>>(deg, off, N_NODES);
    k_fill<<<(N_EDGES + 255) / 256, 256, 0, stream>>>(src, dst, off, cur, ssrc, N_EDGES);

    const float* hin = x;
    float* hbuf[2] = {h0, h1};
    int din = IN_FEATS;
    for (int l = 0; l < 5; ++l) {
        k_gemm<<<(N_NODES + 31) / 32, 192, 0, stream>>>(hin, W[l], al[l], ar[l],
                                                        feat, el, er, N_NODES, din);
        float* hn = hbuf[l & 1];
        k_agg<<<(N_NODES * 64 + 255) / 256, 256, 0, stream>>>(off, ssrc, el, er, feat, b[l], hn, N_NODES);
        hin = hn;
        din = HID;
    }
    k_out<<<(N_NODES + 31) / 32, 256, 0, stream>>>(hin, Wo, bo, out, N_NODES);
}

// Round 3
// 882.639 us; speedup vs baseline: 1.7725x; 1.3834x over previous
//
#include <hip/hip_runtime.h>
#include <cstdint>

#define N_NODES 50000
#define N_EDGES 800000
#define IN_FEATS 128
#define HID 64
#define HEADS 3
#define NUM_CLASSES 8
#define ATTN_SLOPE 0.2f
#define ACT_SLOPE 0.01f

__device__ __forceinline__ float lrelu(float x, float s) { return x > 0.f ? x : s * x; }

// ---------- CSR build (once per call; edges are layer-invariant) ----------
__global__ void k_deg(const int* __restrict__ dst, int* __restrict__ deg, int E) {
    int i = blockIdx.x * blockDim.x + threadIdx.x;
    if (i < E) atomicAdd(&deg[dst[i]], 1);
}

__global__ void k_scan(const int* __restrict__ deg, int* __restrict__ off, int n) {
    __shared__ int tmp[1024];
    __shared__ int carry_s;
    int tid = threadIdx.x;
    if (tid == 0) carry_s = 0;
    __syncthreads();
    for (int base = 0; base < n; base += 1024) {
        int i = base + tid;
        int v = (i < n) ? deg[i] : 0;
        tmp[tid] = v;
        __syncthreads();
        for (int o = 1; o < 1024; o <<= 1) {
            int t = (tid >= o) ? tmp[tid - o] : 0;
            __syncthreads();
            tmp[tid] += t;
            __syncthreads();
        }
        if (i < n) off[i] = carry_s + tmp[tid] - v;
        int tot = tmp[1023];
        __syncthreads();
        if (tid == 0) carry_s += tot;
        __syncthreads();
    }
    if (tid == 0) off[n] = carry_s;
}

__global__ void k_fill(const int* __restrict__ src, const int* __restrict__ dst,
                       const int* __restrict__ off, int* __restrict__ cur,
                       int* __restrict__ ssrc, int E) {
    int i = blockIdx.x * blockDim.x + threadIdx.x;
    if (i < E) {
        int d = dst[i];
        int p = atomicAdd(&cur[d], 1);
        ssrc[off[d] + p] = src[i];
    }
}

// ---------- feat = h @ W, register-microtiled, fused el/er ----------
// Tile: 128 rows x 64 cols (blockIdx.y = head). 256 threads, each 8 rows x 4 cols.
// Per 4-k step: 12 ds_read_b128 -> 128 FMAs (VALU-bound, not LDS-bound).
__global__ __launch_bounds__(256) void k_gemm(const float* __restrict__ h, const float* __restrict__ W,
                                              const float* __restrict__ al, const float* __restrict__ ar,
                                              float* __restrict__ feat,
                                              float* __restrict__ el, float* __restrict__ er,
                                              int N, int din) {
    __shared__ float Hl[128][68];   // stride 68: row-groups hit distinct bank quads
    __shared__ float Wl[64][64];    // [k][col]; k uniform per read -> 2-way conflict (free)
    int tid = threadIdx.x;
    int cg = tid & 15;              // col group: cols cg*4 .. cg*4+3
    int rg = tid >> 4;              // row group: rows rg + 16*i
    int row0 = blockIdx.x * 128;
    int head = blockIdx.y;
    int c0 = head * 64;

    float acc[8][4];
#pragma unroll
    for (int i = 0; i < 8; ++i)
#pragma unroll
        for (int c = 0; c < 4; ++c) acc[i][c] = 0.f;

    for (int k0 = 0; k0 < din; k0 += 64) {
        // stage W chunk: [64k x 64c]
        for (int j = tid; j < 1024; j += 256) {
            int k = j >> 4, c4 = (j & 15) << 2;
            *(float4*)&Wl[k][c4] = *(const float4*)&W[(size_t)(k0 + k) * 192 + c0 + c4];
        }
        // stage H chunk: [128r x 64k]
        for (int j = tid; j < 2048; j += 256) {
            int r = j >> 4, kk = (j & 15) << 2;
            int row = row0 + r;
            float4 v = make_float4(0.f, 0.f, 0.f, 0.f);
            if (row < N) v = *(const float4*)&h[(size_t)row * din + k0 + kk];
            *(float4*)&Hl[r][kk] = v;
        }
        __syncthreads();

        for (int k = 0; k < 64; k += 4) {
            float4 w0 = *(const float4*)&Wl[k + 0][cg << 2];
            float4 w1 = *(const float4*)&Wl[k + 1][cg << 2];
            float4 w2 = *(const float4*)&Wl[k + 2][cg << 2];
            float4 w3 = *(const float4*)&Wl[k + 3][cg << 2];
#pragma unroll
            for (int i = 0; i < 8; ++i) {
                float4 hv = *(const float4*)&Hl[rg + 16 * i][k];
                acc[i][0] += hv.x * w0.x + hv.y * w1.x + hv.z * w2.x + hv.w * w3.x;
                acc[i][1] += hv.x * w0.y + hv.y * w1.y + hv.z * w2.y + hv.w * w3.y;
                acc[i][2] += hv.x * w0.z + hv.y * w1.z + hv.z * w2.z + hv.w * w3.z;
                acc[i][3] += hv.x * w0.w + hv.y * w1.w + hv.z * w2.w + hv.w * w3.w;
            }
        }
        __syncthreads();
    }

    // epilogue: store feat + fused el/er for this head
    float alv0 = al[c0 + (cg << 2) + 0], alv1 = al[c0 + (cg << 2) + 1];
    float alv2 = al[c0 + (cg << 2) + 2], alv3 = al[c0 + (cg << 2) + 3];
    float arv0 = ar[c0 + (cg << 2) + 0], arv1 = ar[c0 + (cg << 2) + 1];
    float arv2 = ar[c0 + (cg << 2) + 2], arv3 = ar[c0 + (cg << 2) + 3];
#pragma unroll
    for (int i = 0; i < 8; ++i) {
        int row = row0 + rg + 16 * i;
        bool ok = (row < N);   // uniform across the 16-lane shfl group (same rg)
        float4 a4 = make_float4(acc[i][0], acc[i][1], acc[i][2], acc[i][3]);
        if (ok) *(float4*)&feat[(size_t)row * 192 + c0 + (cg << 2)] = a4;
        float pl = a4.x * alv0 + a4.y * alv1 + a4.z * alv2 + a4.w * alv3;
        float pr = a4.x * arv0 + a4.y * arv1 + a4.z * arv2 + a4.w * arv3;
        for (int o = 1; o < 16; o <<= 1) {
            pl += __shfl_xor(pl, o);
            pr += __shfl_xor(pr, o);
        }
        if (ok && cg == 0) {
            el[row * HEADS + head] = pl;
            er[row * HEADS + head] = pr;
        }
    }
}

// ---------- edge softmax + aggregate + bias + leakyrelu + head-mean ----------
__global__ __launch_bounds__(256) void k_agg(const int* __restrict__ off, const int* __restrict__ ssrc,
                                             const float* __restrict__ el, const float* __restrict__ er,
                                             const float* __restrict__ feat, const float* __restrict__ b,
                                             float* __restrict__ hout, int N) {
    __shared__ float4 ebuf[4][64];
    int wib = threadIdx.x >> 6;
    int wid = (blockIdx.x * blockDim.x + threadIdx.x) >> 6;
    int lane = threadIdx.x & 63;
    if (wid >= N) return;
    int start = off[wid], end = off[wid + 1];
    int cnt = end - start;
    float er0 = er[wid * HEADS + 0];
    float er1 = er[wid * HEADS + 1];
    float er2 = er[wid * HEADS + 2];
    float acc0 = 0.f, acc1 = 0.f, acc2 = 0.f;
    float den0 = 0.f, den1 = 0.f, den2 = 0.f;

    if (cnt <= 64) {
        int s0 = 0;
        float ea = -3.4e38f, eb = -3.4e38f, ec = -3.4e38f;
        if (lane < cnt) {
            s0 = ssrc[start + lane];
            ea = lrelu(el[s0 * HEADS + 0] + er0, ATTN_SLOPE);
            eb = lrelu(el[s0 * HEADS + 1] + er1, ATTN_SLOPE);
            ec = lrelu(el[s0 * HEADS + 2] + er2, ATTN_SLOPE);
        }
        float ma = ea, mb = eb, mc = ec;
        for (int o = 32; o > 0; o >>= 1) {
            ma = fmaxf(ma, __shfl_xor(ma, o));
            mb = fmaxf(mb, __shfl_xor(mb, o));
            mc = fmaxf(mc, __shfl_xor(mc, o));
        }
        float xa = (lane < cnt) ? __expf(ea - ma) : 0.f;
        float xb = (lane < cnt) ? __expf(eb - mb) : 0.f;
        float xc = (lane < cnt) ? __expf(ec - mc) : 0.f;
        float da = xa, db = xb, dc = xc;
        for (int o = 32; o > 0; o >>= 1) {
            da += __shfl_xor(da, o);
            db += __shfl_xor(db, o);
            dc += __shfl_xor(dc, o);
        }
        den0 = da; den1 = db; den2 = dc;
        ebuf[wib][lane] = make_float4(__int_as_float(s0), xa, xb, xc);
        for (int t = 0; t < cnt; ++t) {
            float4 v = ebuf[wib][t];
            const float* fr = feat + (size_t)__float_as_int(v.x) * 192;
            acc0 += v.y * fr[lane];
            acc1 += v.z * fr[64 + lane];
            acc2 += v.w * fr[128 + lane];
        }
    } else {
        float ma = -3.4e38f, mb = -3.4e38f, mc = -3.4e38f;
        for (int j = start + lane; j < end; j += 64) {
            int s = ssrc[j];
            ma = fmaxf(ma, lrelu(el[s * HEADS + 0] + er0, ATTN_SLOPE));
            mb = fmaxf(mb, lrelu(el[s * HEADS + 1] + er1, ATTN_SLOPE));
            mc = fmaxf(mc, lrelu(el[s * HEADS + 2] + er2, ATTN_SLOPE));
        }
        for (int o = 32; o > 0; o >>= 1) {
            ma = fmaxf(ma, __shfl_xor(ma, o));
            mb = fmaxf(mb, __shfl_xor(mb, o));
            mc = fmaxf(mc, __shfl_xor(mc, o));
        }
        float da = 0.f, db = 0.f, dc = 0.f;
        for (int j0 = start; j0 < end; j0 += 64) {
            int jj = j0 + lane;
            int s0 = 0;
            float xa = 0.f, xb = 0.f, xc = 0.f;
            if (jj < end) {
                s0 = ssrc[jj];
                xa = __expf(lrelu(el[s0 * HEADS + 0] + er0, ATTN_SLOPE) - ma);
                xb = __expf(lrelu(el[s0 * HEADS + 1] + er1, ATTN_SLOPE) - mb);
                xc = __expf(lrelu(el[s0 * HEADS + 2] + er2, ATTN_SLOPE) - mc);
            }
            da += xa; db += xb; dc += xc;
            ebuf[wib][lane] = make_float4(__int_as_float(s0), xa, xb, xc);
            int c = min(64, end - j0);
            for (int t = 0; t < c; ++t) {
                float4 v = ebuf[wib][t];
                const float* fr = feat + (size_t)__float_as_int(v.x) * 192;
                acc0 += v.y * fr[lane];
                acc1 += v.z * fr[64 + lane];
                acc2 += v.w * fr[128 + lane];
            }
        }
        for (int o = 32; o > 0; o >>= 1) {
            da += __shfl_xor(da, o);
            db += __shfl_xor(db, o);
            dc += __shfl_xor(dc, o);
        }
        den0 = da; den1 = db; den2 = dc;
    }

    float v0 = (cnt > 0) ? acc0 / den0 : 0.f;
    float v1 = (cnt > 0) ? acc1 / den1 : 0.f;
    float v2 = (cnt > 0) ? acc2 / den2 : 0.f;
    float hsum = lrelu(v0 + b[lane], ACT_SLOPE)
               + lrelu(v1 + b[64 + lane], ACT_SLOPE)
               + lrelu(v2 + b[128 + lane], ACT_SLOPE);
    hout[wid * 64 + lane] = hsum * (1.f / 3.f);
}

// ---------- logits = h @ Wo + bo ----------
__global__ __launch_bounds__(256) void k_out(const float* __restrict__ h, const float* __restrict__ Wo,
                                             const float* __restrict__ bo, float* __restrict__ out, int N) {
    __shared__ float Hl[32][65];
    __shared__ float Wl[64 * 8];
    int tid = threadIdx.x;
    int n0 = blockIdx.x * 32;
    for (int i = tid; i < 32 * 64; i += 256) {
        int r = i >> 6, k = i & 63;
        Hl[r][k] = (n0 + r < N) ? h[(n0 + r) * 64 + k] : 0.f;
    }
    for (int i = tid; i < 512; i += 256) Wl[i] = Wo[i];
    __syncthreads();
    int r = tid >> 3, c = tid & 7;
    float acc = 0.f;
    for (int k = 0; k < 64; ++k) acc += Hl[r][k] * Wl[k * 8 + c];
    int row = n0 + r;
    if (row < N) out[row * 8 + c] = acc + bo[c];
}

extern "C" void kernel_launch(void* const* d_in, const int* in_sizes, int n_in,
                              void* d_out, int out_size, void* d_ws, size_t ws_size,
                              hipStream_t stream) {
    const float* x  = (const float*)d_in[0];
    const int* src  = (const int*)d_in[1];
    const int* dst  = (const int*)d_in[2];
    const float *W[5], *b[5], *al[5], *ar[5];
    for (int l = 0; l < 5; ++l) {
        W[l]  = (const float*)d_in[3 + l * 4];
        b[l]  = (const float*)d_in[4 + l * 4];
        al[l] = (const float*)d_in[5 + l * 4];
        ar[l] = (const float*)d_in[6 + l * 4];
    }
    const float* Wo = (const float*)d_in[23];
    const float* bo = (const float*)d_in[24];
    float* out = (float*)d_out;

    char* ws = (char*)d_ws;
    auto alloc = [&](size_t bytes) {
        char* p = ws;
        ws += (bytes + 255) & ~size_t(255);
        return p;
    };
    float* feat = (float*)alloc(sizeof(float) * (size_t)N_NODES * 192);
    float* el   = (float*)alloc(sizeof(float) * (size_t)N_NODES * HEADS);
    float* er   = (float*)alloc(sizeof(float) * (size_t)N_NODES * HEADS);
    float* h0   = (float*)alloc(sizeof(float) * (size_t)N_NODES * 64);
    float* h1   = (float*)alloc(sizeof(float) * (size_t)N_NODES * 64);
    int* deg    = (int*)alloc(sizeof(int) * N_NODES);
    int* off    = (int*)alloc(sizeof(int) * (N_NODES + 1));
    int* cur    = (int*)alloc(sizeof(int) * N_NODES);
    int* ssrc   = (int*)alloc(sizeof(int) * N_EDGES);

    hipMemsetAsync(deg, 0, sizeof(int) * N_NODES, stream);
    hipMemsetAsync(cur, 0, sizeof(int) * N_NODES, stream);
    k_deg<<<(N_EDGES + 255) / 256, 256, 0, stream>>>(dst, deg, N_EDGES);
    k_scan<<<1, 1024, 0, stream>>>(deg, off, N_NODES);
    k_fill<<<(N_EDGES + 255) / 256, 256, 0, stream>>>(src, dst, off, cur, ssrc, N_EDGES);

    const float* hin = x;
    float* hbuf[2] = {h0, h1};
    int din = IN_FEATS;
    for (int l = 0; l < 5; ++l) {
        dim3 ggrid((N_NODES + 127) / 128, HEADS);
        k_gemm<<<ggrid, 256, 0, stream>>>(hin, W[l], al[l], ar[l], feat, el, er, N_NODES, din);
        float* hn = hbuf[l & 1];
        k_agg<<<(N_NODES * 64 + 255) / 256, 256, 0, stream>>>(off, ssrc, el, er, feat, b[l], hn, N_NODES);
        hin = hn;
        din = HID;
    }
    k_out<<<(N_NODES + 31) / 32, 256, 0, stream>>>(hin, Wo, bo, out, N_NODES);
}

// Round 4
// 808.170 us; speedup vs baseline: 1.9358x; 1.0921x over previous
//
#include <hip/hip_runtime.h>
#include <cstdint>

#define N_NODES 50000
#define N_EDGES 800000
#define IN_FEATS 128
#define HID 64
#define HEADS 3
#define NUM_CLASSES 8
#define ATTN_SLOPE 0.2f
#define ACT_SLOPE 0.01f

__device__ __forceinline__ float lrelu(float x, float s) { return x > 0.f ? x : s * x; }

// ---------- CSR build (once per call; edges are layer-invariant) ----------
__global__ void k_deg(const int* __restrict__ dst, int* __restrict__ deg, int E) {
    int i = blockIdx.x * blockDim.x + threadIdx.x;
    if (i < E) atomicAdd(&deg[dst[i]], 1);
}

// hierarchical scan: scan1 (25 blocks x 2048 elems) -> scan2 (1 wave) -> scan3
__global__ __launch_bounds__(256) void k_scan1(const int* __restrict__ deg, int* __restrict__ off,
                                               int* __restrict__ bsum, int n) {
    __shared__ int wtot[4];
    int tid = threadIdx.x;
    int lane = tid & 63, wid = tid >> 6;
    int base = blockIdx.x * 2048 + tid * 8;
    int v[8];
    if (base + 8 <= n) {
        int4 a = *(const int4*)&deg[base];
        int4 b = *(const int4*)&deg[base + 4];
        v[0] = a.x; v[1] = a.y; v[2] = a.z; v[3] = a.w;
        v[4] = b.x; v[5] = b.y; v[6] = b.z; v[7] = b.w;
    } else {
#pragma unroll
        for (int j = 0; j < 8; ++j) v[j] = (base + j < n) ? deg[base + j] : 0;
    }
    int s[8];
    s[0] = v[0];
#pragma unroll
    for (int j = 1; j < 8; ++j) s[j] = s[j - 1] + v[j];
    int t = s[7];
    int incl = t;
    for (int o = 1; o < 64; o <<= 1) {
        int u = __shfl_up(incl, o);
        if (lane >= o) incl += u;
    }
    int excl = incl - t;
    if (lane == 63) wtot[wid] = incl;
    __syncthreads();
    int wprefix = 0;
    for (int w = 0; w < wid; ++w) wprefix += wtot[w];
    int base_off = wprefix + excl;
#pragma unroll
    for (int j = 0; j < 8; ++j)
        if (base + j < n) off[base + j] = base_off + s[j] - v[j];
    if (tid == 0) bsum[blockIdx.x] = wtot[0] + wtot[1] + wtot[2] + wtot[3];
}

__global__ __launch_bounds__(64) void k_scan2(int* __restrict__ bsum, int nb) {
    int tid = threadIdx.x;
    int v = (tid < nb) ? bsum[tid] : 0;
    int incl = v;
    for (int o = 1; o < 64; o <<= 1) {
        int u = __shfl_up(incl, o);
        if (tid >= o) incl += u;
    }
    if (tid < nb) bsum[tid] = incl - v;   // exclusive
}

__global__ __launch_bounds__(256) void k_scan3(int* __restrict__ off, const int* __restrict__ bsum,
                                               int n, int E) {
    int i = blockIdx.x * blockDim.x + threadIdx.x;
    if (i < n) off[i] += bsum[i >> 11];
    if (i == 0) off[n] = E;
}

__global__ void k_fill(const int* __restrict__ src, const int* __restrict__ dst,
                       const int* __restrict__ off, int* __restrict__ cur,
                       int* __restrict__ ssrc, int E) {
    int i = blockIdx.x * blockDim.x + threadIdx.x;
    if (i < E) {
        int d = dst[i];
        int p = atomicAdd(&cur[d], 1);
        ssrc[off[d] + p] = src[i];
    }
}

// ---------- feat = h @ W, register-microtiled, fused el/er ----------
__global__ __launch_bounds__(256) void k_gemm(const float* __restrict__ h, const float* __restrict__ W,
                                              const float* __restrict__ al, const float* __restrict__ ar,
                                              float* __restrict__ feat,
                                              float* __restrict__ el, float* __restrict__ er,
                                              int N, int din) {
    __shared__ float Hl[128][68];
    __shared__ float Wl[64][64];
    int tid = threadIdx.x;
    int cg = tid & 15;
    int rg = tid >> 4;
    int row0 = blockIdx.x * 128;
    int head = blockIdx.y;
    int c0 = head * 64;

    float acc[8][4];
#pragma unroll
    for (int i = 0; i < 8; ++i)
#pragma unroll
        for (int c = 0; c < 4; ++c) acc[i][c] = 0.f;

    for (int k0 = 0; k0 < din; k0 += 64) {
        for (int j = tid; j < 1024; j += 256) {
            int k = j >> 4, c4 = (j & 15) << 2;
            *(float4*)&Wl[k][c4] = *(const float4*)&W[(size_t)(k0 + k) * 192 + c0 + c4];
        }
        for (int j = tid; j < 2048; j += 256) {
            int r = j >> 4, kk = (j & 15) << 2;
            int row = row0 + r;
            float4 v = make_float4(0.f, 0.f, 0.f, 0.f);
            if (row < N) v = *(const float4*)&h[(size_t)row * din + k0 + kk];
            *(float4*)&Hl[r][kk] = v;
        }
        __syncthreads();

        for (int k = 0; k < 64; k += 4) {
            float4 w0 = *(const float4*)&Wl[k + 0][cg << 2];
            float4 w1 = *(const float4*)&Wl[k + 1][cg << 2];
            float4 w2 = *(const float4*)&Wl[k + 2][cg << 2];
            float4 w3 = *(const float4*)&Wl[k + 3][cg << 2];
#pragma unroll
            for (int i = 0; i < 8; ++i) {
                float4 hv = *(const float4*)&Hl[rg + 16 * i][k];
                acc[i][0] += hv.x * w0.x + hv.y * w1.x + hv.z * w2.x + hv.w * w3.x;
                acc[i][1] += hv.x * w0.y + hv.y * w1.y + hv.z * w2.y + hv.w * w3.y;
                acc[i][2] += hv.x * w0.z + hv.y * w1.z + hv.z * w2.z + hv.w * w3.z;
                acc[i][3] += hv.x * w0.w + hv.y * w1.w + hv.z * w2.w + hv.w * w3.w;
            }
        }
        __syncthreads();
    }

    float alv0 = al[c0 + (cg << 2) + 0], alv1 = al[c0 + (cg << 2) + 1];
    float alv2 = al[c0 + (cg << 2) + 2], alv3 = al[c0 + (cg << 2) + 3];
    float arv0 = ar[c0 + (cg << 2) + 0], arv1 = ar[c0 + (cg << 2) + 1];
    float arv2 = ar[c0 + (cg << 2) + 2], arv3 = ar[c0 + (cg << 2) + 3];
#pragma unroll
    for (int i = 0; i < 8; ++i) {
        int row = row0 + rg + 16 * i;
        bool ok = (row < N);
        float4 a4 = make_float4(acc[i][0], acc[i][1], acc[i][2], acc[i][3]);
        if (ok) *(float4*)&feat[(size_t)row * 192 + c0 + (cg << 2)] = a4;
        float pl = a4.x * alv0 + a4.y * alv1 + a4.z * alv2 + a4.w * alv3;
        float pr = a4.x * arv0 + a4.y * arv1 + a4.z * arv2 + a4.w * arv3;
        for (int o = 1; o < 16; o <<= 1) {
            pl += __shfl_xor(pl, o);
            pr += __shfl_xor(pr, o);
        }
        if (ok && cg == 0) {
            el[row * HEADS + head] = pl;
            er[row * HEADS + head] = pr;
        }
    }
}

// ---------- edge softmax + aggregate + bias + leakyrelu + head-mean ----------
// One wave per dst node, lanes = 64 feats, all 3 heads in one edge pass.
// Gather loop unrolled x4: 12 independent 256B gathers in flight per iter.
__global__ __launch_bounds__(256) void k_agg(const int* __restrict__ off, const int* __restrict__ ssrc,
                                             const float* __restrict__ el, const float* __restrict__ er,
                                             const float* __restrict__ feat, const float* __restrict__ b,
                                             float* __restrict__ hout, int N) {
    __shared__ float4 ebuf[4][64];
    int wib = threadIdx.x >> 6;
    int wid = (blockIdx.x * blockDim.x + threadIdx.x) >> 6;
    int lane = threadIdx.x & 63;
    if (wid >= N) return;
    int start = off[wid], end = off[wid + 1];
    int cnt = end - start;
    float er0 = er[wid * HEADS + 0];
    float er1 = er[wid * HEADS + 1];
    float er2 = er[wid * HEADS + 2];
    float acc0 = 0.f, acc1 = 0.f, acc2 = 0.f;
    float den0 = 0.f, den1 = 0.f, den2 = 0.f;

    if (cnt <= 64) {
        int s0 = 0;
        float ea = -3.4e38f, eb = -3.4e38f, ec = -3.4e38f;
        if (lane < cnt) {
            s0 = ssrc[start + lane];
            ea = lrelu(el[s0 * HEADS + 0] + er0, ATTN_SLOPE);
            eb = lrelu(el[s0 * HEADS + 1] + er1, ATTN_SLOPE);
            ec = lrelu(el[s0 * HEADS + 2] + er2, ATTN_SLOPE);
        }
        float ma = ea, mb = eb, mc = ec;
        for (int o = 32; o > 0; o >>= 1) {
            ma = fmaxf(ma, __shfl_xor(ma, o));
            mb = fmaxf(mb, __shfl_xor(mb, o));
            mc = fmaxf(mc, __shfl_xor(mc, o));
        }
        float xa = (lane < cnt) ? __expf(ea - ma) : 0.f;
        float xb = (lane < cnt) ? __expf(eb - mb) : 0.f;
        float xc = (lane < cnt) ? __expf(ec - mc) : 0.f;
        float da = xa, db = xb, dc = xc;
        for (int o = 32; o > 0; o >>= 1) {
            da += __shfl_xor(da, o);
            db += __shfl_xor(db, o);
            dc += __shfl_xor(dc, o);
        }
        den0 = da; den1 = db; den2 = dc;
        ebuf[wib][lane] = make_float4(__int_as_float(s0), xa, xb, xc);
        int t = 0;
        for (; t + 4 <= cnt; t += 4) {
            float4 v0 = ebuf[wib][t + 0];
            float4 v1 = ebuf[wib][t + 1];
            float4 v2 = ebuf[wib][t + 2];
            float4 v3 = ebuf[wib][t + 3];
            const float* f0 = feat + (size_t)__float_as_int(v0.x) * 192 + lane;
            const float* f1 = feat + (size_t)__float_as_int(v1.x) * 192 + lane;
            const float* f2 = feat + (size_t)__float_as_int(v2.x) * 192 + lane;
            const float* f3 = feat + (size_t)__float_as_int(v3.x) * 192 + lane;
            float p00 = f0[0], p01 = f0[64], p02 = f0[128];
            float p10 = f1[0], p11 = f1[64], p12 = f1[128];
            float p20 = f2[0], p21 = f2[64], p22 = f2[128];
            float p30 = f3[0], p31 = f3[64], p32 = f3[128];
            acc0 += v0.y * p00; acc1 += v0.z * p01; acc2 += v0.w * p02;
            acc0 += v1.y * p10; acc1 += v1.z * p11; acc2 += v1.w * p12;
            acc0 += v2.y * p20; acc1 += v2.z * p21; acc2 += v2.w * p22;
            acc0 += v3.y * p30; acc1 += v3.z * p31; acc2 += v3.w * p32;
        }
        for (; t < cnt; ++t) {
            float4 v = ebuf[wib][t];
            const float* fr = feat + (size_t)__float_as_int(v.x) * 192 + lane;
            acc0 += v.y * fr[0];
            acc1 += v.z * fr[64];
            acc2 += v.w * fr[128];
        }
    } else {
        float ma = -3.4e38f, mb = -3.4e38f, mc = -3.4e38f;
        for (int j = start + lane; j < end; j += 64) {
            int s = ssrc[j];
            ma = fmaxf(ma, lrelu(el[s * HEADS + 0] + er0, ATTN_SLOPE));
            mb = fmaxf(mb, lrelu(el[s * HEADS + 1] + er1, ATTN_SLOPE));
            mc = fmaxf(mc, lrelu(el[s * HEADS + 2] + er2, ATTN_SLOPE));
        }
        for (int o = 32; o > 0; o >>= 1) {
            ma = fmaxf(ma, __shfl_xor(ma, o));
            mb = fmaxf(mb, __shfl_xor(mb, o));
            mc = fmaxf(mc, __shfl_xor(mc, o));
        }
        float da = 0.f, db = 0.f, dc = 0.f;
        for (int j0 = start; j0 < end; j0 += 64) {
            int jj = j0 + lane;
            int s0 = 0;
            float xa = 0.f, xb = 0.f, xc = 0.f;
            if (jj < end) {
                s0 = ssrc[jj];
                xa = __expf(lrelu(el[s0 * HEADS + 0] + er0, ATTN_SLOPE) - ma);
                xb = __expf(lrelu(el[s0 * HEADS + 1] + er1, ATTN_SLOPE) - mb);
                xc = __expf(lrelu(el[s0 * HEADS + 2] + er2, ATTN_SLOPE) - mc);
            }
            da += xa; db += xb; dc += xc;
            ebuf[wib][lane] = make_float4(__int_as_float(s0), xa, xb, xc);
            int c = min(64, end - j0);
            int t = 0;
            for (; t + 4 <= c; t += 4) {
                float4 v0 = ebuf[wib][t + 0];
                float4 v1 = ebuf[wib][t + 1];
                float4 v2 = ebuf[wib][t + 2];
                float4 v3 = ebuf[wib][t + 3];
                const float* f0 = feat + (size_t)__float_as_int(v0.x) * 192 + lane;
                const float* f1 = feat + (size_t)__float_as_int(v1.x) * 192 + lane;
                const float* f2 = feat + (size_t)__float_as_int(v2.x) * 192 + lane;
                const float* f3 = feat + (size_t)__float_as_int(v3.x) * 192 + lane;
                float p00 = f0[0], p01 = f0[64], p02 = f0[128];
                float p10 = f1[0], p11 = f1[64], p12 = f1[128];
                float p20 = f2[0], p21 = f2[64], p22 = f2[128];
                float p30 = f3[0], p31 = f3[64], p32 = f3[128];
                acc0 += v0.y * p00; acc1 += v0.z * p01; acc2 += v0.w * p02;
                acc0 += v1.y * p10; acc1 += v1.z * p11; acc2 += v1.w * p12;
                acc0 += v2.y * p20; acc1 += v2.z * p21; acc2 += v2.w * p22;
                acc0 += v3.y * p30; acc1 += v3.z * p31; acc2 += v3.w * p32;
            }
            for (; t < c; ++t) {
                float4 v = ebuf[wib][t];
                const float* fr = feat + (size_t)__float_as_int(v.x) * 192 + lane;
                acc0 += v.y * fr[0];
                acc1 += v.z * fr[64];
                acc2 += v.w * fr[128];
            }
        }
        for (int o = 32; o > 0; o >>= 1) {
            da += __shfl_xor(da, o);
            db += __shfl_xor(db, o);
            dc += __shfl_xor(dc, o);
        }
        den0 = da; den1 = db; den2 = dc;
    }

    float v0 = (cnt > 0) ? acc0 / den0 : 0.f;
    float v1 = (cnt > 0) ? acc1 / den1 : 0.f;
    float v2 = (cnt > 0) ? acc2 / den2 : 0.f;
    float hsum = lrelu(v0 + b[lane], ACT_SLOPE)
               + lrelu(v1 + b[64 + lane], ACT_SLOPE)
               + lrelu(v2 + b[128 + lane], ACT_SLOPE);
    hout[wid * 64 + lane] = hsum * (1.f / 3.f);
}

// ---------- logits = h @ Wo + bo ----------
__global__ __launch_bounds__(256) void k_out(const float* __restrict__ h, const float* __restrict__ Wo,
                                             const float* __restrict__ bo, float* __restrict__ out, int N) {
    __shared__ float Hl[32][65];
    __shared__ float Wl[64 * 8];
    int tid = threadIdx.x;
    int n0 = blockIdx.x * 32;
    for (int i = tid; i < 32 * 64; i += 256) {
        int r = i >> 6, k = i & 63;
        Hl[r][k] = (n0 + r < N) ? h[(n0 + r) * 64 + k] : 0.f;
    }
    for (int i = tid; i < 512; i += 256) Wl[i] = Wo[i];
    __syncthreads();
    int r = tid >> 3, c = tid & 7;
    float acc = 0.f;
    for (int k = 0; k < 64; ++k) acc += Hl[r][k] * Wl[k * 8 + c];
    int row = n0 + r;
    if (row < N) out[row * 8 + c] = acc + bo[c];
}

extern "C" void kernel_launch(void* const* d_in, const int* in_sizes, int n_in,
                              void* d_out, int out_size, void* d_ws, size_t ws_size,
                              hipStream_t stream) {
    const float* x  = (const float*)d_in[0];
    const int* src  = (const int*)d_in[1];
    const int* dst  = (const int*)d_in[2];
    const float *W[5], *b[5], *al[5], *ar[5];
    for (int l = 0; l < 5; ++l) {
        W[l]  = (const float*)d_in[3 + l * 4];
        b[l]  = (const float*)d_in[4 + l * 4];
        al[l] = (const float*)d_in[5 + l * 4];
        ar[l] = (const float*)d_in[6 + l * 4];
    }
    const float* Wo = (const float*)d_in[23];
    const float* bo = (const float*)d_in[24];
    float* out = (float*)d_out;

    char* ws = (char*)d_ws;
    auto alloc = [&](size_t bytes) {
        char* p = ws;
        ws += (bytes + 255) & ~size_t(255);
        return p;
    };
    float* feat = (float*)alloc(sizeof(float) * (size_t)N_NODES * 192);
    float* el   = (float*)alloc(sizeof(float) * (size_t)N_NODES * HEADS);
    float* er   = (float*)alloc(sizeof(float) * (size_t)N_NODES * HEADS);
    float* h0   = (float*)alloc(sizeof(float) * (size_t)N_NODES * 64);
    float* h1   = (float*)alloc(sizeof(float) * (size_t)N_NODES * 64);
    int* deg    = (int*)alloc(sizeof(int) * N_NODES);
    int* off    = (int*)alloc(sizeof(int) * (N_NODES + 1));
    int* cur    = (int*)alloc(sizeof(int) * N_NODES);
    int* ssrc   = (int*)alloc(sizeof(int) * N_EDGES);
    int* bsum   = (int*)alloc(sizeof(int) * 64);

    const int NB = (N_NODES + 2047) / 2048;   // 25 (<=64 required by k_scan2)
    hipMemsetAsync(deg, 0, sizeof(int) * N_NODES, stream);
    hipMemsetAsync(cur, 0, sizeof(int) * N_NODES, stream);
    k_deg<<<(N_EDGES + 255) / 256, 256, 0, stream>>>(dst, deg, N_EDGES);
    k_scan1<<<NB, 256, 0, stream>>>(deg, off, bsum, N_NODES);
    k_scan2<<<1, 64, 0, stream>>>(bsum, NB);
    k_scan3<<<(N_NODES + 255) / 256, 256, 0, stream>>>(off, bsum, N_NODES, N_EDGES);
    k_fill<<<(N_EDGES + 255) / 256, 256, 0, stream>>>(src, dst, off, cur, ssrc, N_EDGES);

    const float* hin = x;
    float* hbuf[2] = {h0, h1};
    int din = IN_FEATS;
    for (int l = 0; l < 5; ++l) {
        dim3 ggrid((N_NODES + 127) / 128, HEADS);
        k_gemm<<<ggrid, 256, 0, stream>>>(hin, W[l], al[l], ar[l], feat, el, er, N_NODES, din);
        float* hn = hbuf[l & 1];
        k_agg<<<(N_NODES * 64 + 255) / 256, 256, 0, stream>>>(off, ssrc, el, er, feat, b[l], hn, N_NODES);
        hin = hn;
        din = HID;
    }
    k_out<<<(N_NODES + 31) / 32, 256, 0, stream>>>(hin, Wo, bo, out, N_NODES);
}